// Round 13
// baseline (387.043 us; speedup 1.0000x reference)
//
#include <hip/hip_runtime.h>
#include <math.h>

#define GG   10000
#define NN0  32
#define EE0  64
#define NFF  64
#define HH   128
#define DD   256
#define BB   4096
#define E2B  8192
#define SIXH 768
#define APAD 36
#define XTS  36

typedef unsigned short u16;
typedef __attribute__((ext_vector_type(8))) short short8v;
typedef __attribute__((ext_vector_type(4))) short short4v;
typedef __attribute__((ext_vector_type(4))) float f32x4;
typedef _Float16 h8f __attribute__((ext_vector_type(8)));
typedef _Float16 h4f __attribute__((ext_vector_type(4)));

#define WSYNC() do { __builtin_amdgcn_wave_barrier(); __builtin_amdgcn_sched_barrier(0); } while (0)

static __device__ __forceinline__ u16 f2bf(float x) {
  unsigned u = __float_as_uint(x);
  return (u16)((u + 0x7FFFu + ((u >> 16) & 1u)) >> 16);   // RTNE
}
static __device__ __forceinline__ float bf2f(u16 h) {
  return __uint_as_float(((unsigned)h) << 16);
}

// ============================================================
// Per-graph pipeline, 3 barrier-phases per stage:
//  A: [readout prev] + [zero A-next] + MFMA-1 (B' in registers)
//  B: MFMA-2 (y@W) -> Xt + v1/v2 slot partials
//  C: wave-0 serial: score->rank->inv->remap->A[next] atomics->dis->cm
// fp16 hi/lo 3-product scheme throughout (fp32-class error).
// ~37.6 KB LDS -> 4 blocks/CU; 11 barriers/graph (was 21).
// ============================================================

template<int M, int KK, int PREVKK, int K, int KP, bool LAST>
__device__ __forceinline__ void stage(
    const _Float16* __restrict__ WTh, const _Float16* __restrict__ WTl,
    const float* __restrict__ bg,
    const float* __restrict__ Wr, const float* __restrict__ Wn, const float* __restrict__ bs,
    _Float16* Xth, _Float16* Xtl, _Float16* ybh, _Float16* ybl,
    float* s_Acur, float* s_Anext,
    float* s_dis, float* s_score, float* s_cm, int* s_rk, int* s_inv,
    float* s_v1p, float* s_v2p,
    int& src_r, int& dst_r, float& ew_r,
    u16* __restrict__ featg_prev, int t)
{
  constexpr int RT  = (M > 16) ? 2 : 1;
  constexpr int CTW = (RT == 2) ? 4 : 2;
  constexpr int KF  = K / 32;
  constexpr int NS  = (RT == 2) ? 2 : 4;
  const int l = t & 63, w = t >> 6;
  const int l15 = l & 15, kb = l >> 4;

  // ================= Phase A =================
  if constexpr (PREVKK > 0) {     // deferred readout of previous stage
    const int f = t & 127, which = t >> 7;
    float acc = which ? 0.f : -INFINITY;
#pragma unroll
    for (int r = 0; r < PREVKK; ++r) {
      const int n = s_inv[r];
      const float v = (float)Xth[f*XTS + n] * s_score[n];
      acc = which ? (acc + v) : fmaxf(acc, v);
    }
    featg_prev[which*HH + f] = f2bf(which ? acc * (1.f/PREVKK) : acc);
  }
  if constexpr (!LAST) {          // zero A[next] for phase-C atomics
    for (int idx = t; idx < NN0*APAD/4; idx += 256) {
      float4 z4; z4.x=0.f; z4.y=0.f; z4.z=0.f; z4.w=0.f;
      *(float4*)(s_Anext + idx*4) = z4;
    }
  }
  // MFMA-1: y[r][f] = sum_p B'[r][p]·X[p][f], B' built in registers
#pragma unroll
  for (int s2 = 0; s2 < 2; ++s2) {
    const int it = (RT == 2) ? s2 : 0;
    const int jt = (RT == 2) ? w : (2*w + s2);
    const int r  = it*16 + l15;
    const float dr = s_dis[r];
    h8f ah, al;
    {
      const int p0 = kb*8;
      const int4   rkA = *(const int4*)(s_rk + p0);
      const int4   rkB = *(const int4*)(s_rk + p0 + 4);
      const float4 cmA = *(const float4*)(s_cm + p0);
      const float4 cmB = *(const float4*)(s_cm + p0 + 4);
#pragma unroll
      for (int j = 0; j < 8; ++j) {
        const int   rk = (j==0)?rkA.x:(j==1)?rkA.y:(j==2)?rkA.z:(j==3)?rkA.w
                        :(j==4)?rkB.x:(j==5)?rkB.y:(j==6)?rkB.z:rkB.w;
        const float cm = (j==0)?cmA.x:(j==1)?cmA.y:(j==2)?cmA.z:(j==3)?cmA.w
                        :(j==4)?cmB.x:(j==5)?cmB.y:(j==6)?cmB.z:cmB.w;
        const float a = s_Acur[r*APAD + rk];
        const float c = dr * cm * (a + ((rk == r) ? 1.f : 0.f));
        const _Float16 h = (_Float16)c;
        ah[j] = h;
        al[j] = (_Float16)((c - (float)h) * 2048.f);
      }
    }
    const int f = jt*16 + l15;
    h8f bh, bl;
    {
      const h4f x0 = *(const h4f*)(Xth + f*XTS + kb*8);
      const h4f x1 = *(const h4f*)(Xth + f*XTS + kb*8 + 4);
      const h4f y0 = *(const h4f*)(Xtl + f*XTS + kb*8);
      const h4f y1 = *(const h4f*)(Xtl + f*XTS + kb*8 + 4);
#pragma unroll
      for (int u = 0; u < 4; ++u) {
        bh[u] = x0[u]; bh[u+4] = x1[u];
        bl[u] = y0[u]; bl[u+4] = y1[u];
      }
    }
    f32x4 a0 = {0.f,0.f,0.f,0.f}, a1 = {0.f,0.f,0.f,0.f};
    a0 = __builtin_amdgcn_mfma_f32_16x16x32_f16(ah, bh, a0, 0, 0, 0);
    a1 = __builtin_amdgcn_mfma_f32_16x16x32_f16(ah, bl, a1, 0, 0, 0);
    a1 = __builtin_amdgcn_mfma_f32_16x16x32_f16(al, bh, a1, 0, 0, 0);
#pragma unroll
    for (int j = 0; j < 4; ++j) {
      const int rr = it*16 + kb*4 + j;
      const float v = fmaf(a1[j], (1.f/2048.f), a0[j]);
      const _Float16 h = (_Float16)v;
      ybh[rr*KP + f] = h;
      ybl[rr*KP + f] = (_Float16)((v - (float)h) * 2048.f);
    }
  }
  __syncthreads();

  // ================= Phase B: MFMA-2 =================
  {
    const int rt   = (RT == 2) ? (w >> 1) : 0;
    const int ct0  = (RT == 2) ? ((w & 1) * CTW) : (w * CTW);
    const int slot = (RT == 2) ? (w & 1) : w;

    h8f ah[KF], al[KF];
#pragma unroll
    for (int kf = 0; kf < KF; ++kf) {
      ah[kf] = *(const h8f*)(ybh + (rt*16 + l15)*KP + kf*32 + kb*8);
      al[kf] = *(const h8f*)(ybl + (rt*16 + l15)*KP + kf*32 + kb*8);
    }
    float p1[4] = {0.f,0.f,0.f,0.f}, p2[4] = {0.f,0.f,0.f,0.f};
#pragma unroll
    for (int ci = 0; ci < CTW; ++ci) {
      const int col = (ct0 + ci)*16 + l15;
      f32x4 a0 = {0.f,0.f,0.f,0.f}, a1 = {0.f,0.f,0.f,0.f};
#pragma unroll
      for (int kf = 0; kf < KF; ++kf) {
        const h8f bh = *(const h8f*)(WTh + (size_t)col*K + kf*32 + kb*8);
        const h8f bl = *(const h8f*)(WTl + (size_t)col*K + kf*32 + kb*8);
        a0 = __builtin_amdgcn_mfma_f32_16x16x32_f16(ah[kf], bh, a0, 0, 0, 0);
        a1 = __builtin_amdgcn_mfma_f32_16x16x32_f16(ah[kf], bl, a1, 0, 0, 0);
        a1 = __builtin_amdgcn_mfma_f32_16x16x32_f16(al[kf], bh, a1, 0, 0, 0);
      }
      const float bb = bg[col], wnc = Wn[col], wrc = Wr[col];
#pragma unroll
      for (int j = 0; j < 4; ++j) {
        const int row = rt*16 + kb*4 + j;
        const float o = fmaxf(fmaf(a1[j], (1.f/2048.f), a0[j]) + bb, 0.f);
        const _Float16 h = (_Float16)o;
        Xth[col*XTS + row] = h;
        Xtl[col*XTS + row] = (_Float16)((o - (float)h) * 2048.f);
        p1[j] = fmaf(o, wnc, p1[j]);
        p2[j] = fmaf(o, wrc, p2[j]);
      }
    }
#pragma unroll
    for (int j = 0; j < 4; ++j) {
#pragma unroll
      for (int off = 8; off >= 1; off >>= 1) {
        p1[j] += __shfl_xor(p1[j], off);
        p2[j] += __shfl_xor(p2[j], off);
      }
    }
    if (l15 == 0) {
#pragma unroll
      for (int j = 0; j < 4; ++j) {
        const int row = rt*16 + kb*4 + j;
        s_v1p[slot*32 + row] = p1[j];
        s_v2p[slot*32 + row] = p2[j];
      }
    }
  }
  __syncthreads();

  // ================= Phase C (wave 0, wave-synchronous) =================
  if (t < 64) {
    float sc_own = 0.f;
    int   rank   = 0;
    if (t < M) {
      float v2t = s_v2p[t] + s_v2p[32 + t];
      if (NS == 4) v2t += s_v2p[64 + t] + s_v2p[96 + t];
      float sc = bs[0] + v2t;
#pragma unroll
      for (int m0 = 0; m0 < M; m0 += 4) {
        const float4 a4 = *(const float4*)(s_Acur + t*APAD + m0);
        float4 v4 = *(const float4*)(s_v1p + m0);
        const float4 vb = *(const float4*)(s_v1p + 32 + m0);
        v4.x += vb.x; v4.y += vb.y; v4.z += vb.z; v4.w += vb.w;
        if (NS == 4) {
          const float4 vc = *(const float4*)(s_v1p + 64 + m0);
          const float4 vd = *(const float4*)(s_v1p + 96 + m0);
          v4.x += vc.x + vd.x; v4.y += vc.y + vd.y;
          v4.z += vc.z + vd.z; v4.w += vc.w + vd.w;
        }
        sc += a4.x*v4.x + a4.y*v4.y + a4.z*v4.z + a4.w*v4.w;
      }
      sc_own = tanhf(sc);
      s_score[t] = sc_own;
    }
    WSYNC();
    if (t < M) {
      int r = 0;
#pragma unroll
      for (int m0 = 0; m0 < M; m0 += 4) {
        const float4 s4 = *(const float4*)(s_score + m0);
#pragma unroll
        for (int q = 0; q < 4; ++q) {
          const float sm = (q==0)?s4.x:(q==1)?s4.y:(q==2)?s4.z:s4.w;
          r += (sm > sc_own) || (sm == sc_own && (m0+q) < t);
        }
      }
      rank = r;
      if (r < KK) s_inv[r] = t;
    }
    if constexpr (!LAST) {
      // edge remap via cross-lane rank lookup, then A[next] atomics
      const int a = __shfl(rank, src_r);
      const int b = __shfl(rank, dst_r);
      const bool val = (a < KK) && (b < KK);
      ew_r  = val ? ew_r : 0.f;
      src_r = val ? a : 0;
      dst_r = val ? b : 0;
      atomicAdd(&s_Anext[dst_r*APAD + src_r], ew_r);
      WSYNC();
      if (t < 16) {
        float deg = 1.f;
#pragma unroll
        for (int m0 = 0; m0 < 32; m0 += 4) {
          const float4 a4 = *(const float4*)(s_Anext + t*APAD + m0);
          deg += a4.x + a4.y + a4.z + a4.w;
        }
        s_dis[t] = rsqrtf(deg);
      }
      WSYNC();
      if (t < 32) {
        const bool valid = (t < M) && (rank < KK);
        s_rk[t] = valid ? rank : 0;
        s_cm[t] = valid ? s_dis[rank] * sc_own : 0.f;
      }
    }
  }
  __syncthreads();
}

__global__ __launch_bounds__(256, 4) void graph_kernel(
    const float* __restrict__ x,
    const int* __restrict__ esrc, const int* __restrict__ edst, const float* __restrict__ ewg,
    const _Float16* __restrict__ WT,
    const float* __restrict__ b1,
    const float* __restrict__ Ws1r, const float* __restrict__ Ws1n, const float* __restrict__ bs1,
    const float* __restrict__ b2,
    const float* __restrict__ Ws2r, const float* __restrict__ Ws2n, const float* __restrict__ bs2,
    const float* __restrict__ b3,
    const float* __restrict__ Ws3r, const float* __restrict__ Ws3n, const float* __restrict__ bs3,
    u16* __restrict__ featB)
{
  __shared__ __align__(16) _Float16 Xth[128*XTS], Xtl[128*XTS];   // 18.4 KB
  __shared__ __align__(16) _Float16 ybh[2304], ybl[2304];         // 9.2 KB
  __shared__ __align__(16) float s_A[2][NN0*APAD];                // 9.2 KB
  __shared__ __align__(16) float s_v1p[128], s_v2p[128];
  __shared__ __align__(16) float s_dis[NN0], s_score[NN0], s_cm[NN0];
  __shared__ __align__(16) int   s_rk[NN0], s_inv[16];

  const int t = threadIdx.x;
  const int g = blockIdx.x;

  // init: x -> Xt (fp16 h/l transposed), edges -> regs, zero A[0]
#pragma unroll
  for (int q = 0; q < 8; ++q) {
    const int idx = q*256 + t;
    const int p = idx >> 6, f = idx & 63;
    const float v = x[(size_t)g*(NN0*NFF) + idx];
    const _Float16 h = (_Float16)v;
    Xth[f*XTS + p] = h;
    Xtl[f*XTS + p] = (_Float16)((v - (float)h) * 2048.f);
  }
  int src_r, dst_r; float ew_r;
  {
    const int e = g*EE0 + (t & 63);
    src_r = esrc[e] - g*NN0;
    dst_r = edst[e] - g*NN0;
    ew_r  = ewg[e];
  }
  for (int idx = t; idx < NN0*APAD/4; idx += 256) {
    float4 z4; z4.x=0.f; z4.y=0.f; z4.z=0.f; z4.w=0.f;
    *(float4*)(s_A[0] + idx*4) = z4;
  }
  __syncthreads();

  // C0 (wave 0): A[0] atomics (raw ids) -> dis -> cm/rk identity
  if (t < 64) {
    atomicAdd(&s_A[0][dst_r*APAD + src_r], ew_r);
    WSYNC();
    if (t < 32) {
      float deg = 1.f;
#pragma unroll
      for (int m0 = 0; m0 < 32; m0 += 4) {
        const float4 a4 = *(const float4*)(s_A[0] + t*APAD + m0);
        deg += a4.x + a4.y + a4.z + a4.w;
      }
      const float dis = rsqrtf(deg);
      s_dis[t] = dis;
      s_cm[t]  = dis;
      s_rk[t]  = t;
    }
  }
  __syncthreads();

  u16* featg = featB + (size_t)g * SIXH;
  const _Float16* W1h = WT;
  const _Float16* W1l = W1h + 128*64;
  const _Float16* W2h = W1l + 128*64;
  const _Float16* W2l = W2h + 128*128;
  const _Float16* W3h = W2l + 128*128;
  const _Float16* W3l = W3h + 128*128;

  stage<32, 16, 0,  64,  72, false>(W1h, W1l, b1, Ws1r, Ws1n, bs1,
      Xth, Xtl, ybh, ybl, s_A[0], s_A[1], s_dis, s_score, s_cm, s_rk, s_inv,
      s_v1p, s_v2p, src_r, dst_r, ew_r, featg, t);
  stage<16,  8, 16, 128, 136, false>(W2h, W2l, b2, Ws2r, Ws2n, bs2,
      Xth, Xtl, ybh, ybl, s_A[1], s_A[0], s_dis, s_score, s_cm, s_rk, s_inv,
      s_v1p, s_v2p, src_r, dst_r, ew_r, featg, t);
  stage< 8,  4,  8, 128, 136, true >(W3h, W3l, b3, Ws3r, Ws3n, bs3,
      Xth, Xtl, ybh, ybl, s_A[0], s_A[1], s_dis, s_score, s_cm, s_rk, s_inv,
      s_v1p, s_v2p, src_r, dst_r, ew_r, featg + 256, t);

  // final readout (stage 3, KK=4)
  {
    const int f = t & 127, which = t >> 7;
    float acc = which ? 0.f : -INFINITY;
#pragma unroll
    for (int r = 0; r < 4; ++r) {
      const int n = s_inv[r];
      const float v = (float)Xth[f*XTS + n] * s_score[n];
      acc = which ? (acc + v) : fmaxf(acc, v);
    }
    featg[512 + which*HH + f] = f2bf(which ? acc * 0.25f : acc);
  }
}

// convert graph-stage weights into fp16 hi/lo, fragment-transposed [col][k]
__global__ void k_convW123(const float* __restrict__ W1, const float* __restrict__ W2,
                           const float* __restrict__ W3, _Float16* __restrict__ T)
{
  const int c = blockIdx.x;
  const int k = threadIdx.x;
  _Float16* W1h = T;
  _Float16* W1l = W1h + 128*64;
  _Float16* W2h = W1l + 128*64;
  _Float16* W2l = W2h + 128*128;
  _Float16* W3h = W2l + 128*128;
  _Float16* W3l = W3h + 128*128;
  if (k < 64) {
    const float v = W1[(size_t)k*HH + c];
    const _Float16 h = (_Float16)v;
    W1h[c*64 + k] = h;
    W1l[c*64 + k] = (_Float16)((v - (float)h) * 2048.f);
  }
  {
    const float v = W2[(size_t)k*HH + c];
    const _Float16 h = (_Float16)v;
    W2h[c*HH + k] = h;
    W2l[c*HH + k] = (_Float16)((v - (float)h) * 2048.f);
  }
  {
    const float v = W3[(size_t)k*HH + c];
    const _Float16 h = (_Float16)v;
    W3h[c*HH + k] = h;
    W3l[c*HH + k] = (_Float16)((v - (float)h) * 2048.f);
  }
}

// ============================================================
// DDI stage — bf16 MFMA GEMMs (unchanged)
// ============================================================

__global__ void k_convW(const float* __restrict__ Wd,
                        const float* __restrict__ Wl1, const float* __restrict__ Wl2,
                        u16* __restrict__ WdT, u16* __restrict__ WlT)
{
  const int b = blockIdx.x, t = threadIdx.x;
  if (b < 256) {
#pragma unroll
    for (int i = 0; i < 3; ++i) {
      const int k = i*256 + t;
      WdT[(size_t)b*SIXH + k] = f2bf(Wd[(size_t)k*DD + b]);
    }
  } else {
    const int c = b - 256;
    const float* src = (c < 256) ? Wl1 : Wl2;
    WlT[(size_t)c*DD + t] = f2bf(src[(size_t)t*DD + (c & 255)]);
  }
}

__global__ void k_deg_init(float* __restrict__ degf) {
  int i = blockIdx.x*256 + threadIdx.x;
  if (i < GG) degf[i] = 1.f;
}

__global__ void k_deg_acc(const int* __restrict__ ddi, float* __restrict__ degf) {
  int e = blockIdx.x*256 + threadIdx.x;
  if (e < E2B) atomicAdd(&degf[ddi[E2B + e]], 1.f);
}

__global__ __launch_bounds__(256) void k_ddi_mfma(const u16* __restrict__ featB,
    const u16* __restrict__ WdT, const float* __restrict__ degf,
    const float* __restrict__ bd, float* __restrict__ hdd, float* __restrict__ z)
{
  const int t = threadIdx.x;
  const int l = t & 63, w = t >> 6;
  const int r0 = blockIdx.x * 16;
  const int l15 = l & 15, kb = l >> 4;
  const int c0 = w * 64;
  f32x4 acc[4];
#pragma unroll
  for (int fi = 0; fi < 4; ++fi) { acc[fi][0]=0.f; acc[fi][1]=0.f; acc[fi][2]=0.f; acc[fi][3]=0.f; }
  const u16* aptr = featB + (size_t)(r0 + l15)*SIXH + kb*8;
#pragma unroll 2
  for (int kk = 0; kk < SIXH; kk += 32) {
    const short8v a = *(const short8v*)(aptr + kk);
#pragma unroll
    for (int fi = 0; fi < 4; ++fi) {
      const short8v b = *(const short8v*)(WdT + (size_t)(c0 + fi*16 + l15)*SIXH + kk + kb*8);
      acc[fi] = __builtin_amdgcn_mfma_f32_16x16x32_bf16(a, b, acc[fi], 0, 0, 0);
    }
  }
#pragma unroll
  for (int j = 0; j < 4; ++j) {
    const int gr = r0 + kb*4 + j;
    const float rd = 1.f / degf[gr];
#pragma unroll
    for (int fi = 0; fi < 4; ++fi) {
      const int c = c0 + fi*16 + l15;
      const float v = acc[fi][j];
      hdd[(size_t)gr*DD + c] = v;
      z[(size_t)gr*DD + c] = fmaf(v, rd, bd[c]);
    }
  }
}

__global__ void k_scatter(const int* __restrict__ ddi, const float* __restrict__ degf,
                          const float* __restrict__ hdd, float* __restrict__ z)
{
  const int t = threadIdx.x;
#pragma unroll
  for (int j = 0; j < 4; ++j) {
    const int e = blockIdx.x*4 + j;
    const int s = ddi[e], d = ddi[E2B + e];
    const float nrm = rsqrtf(degf[s]) * rsqrtf(degf[d]);
    atomicAdd(&z[(size_t)d*DD + t], nrm * hdd[(size_t)s*DD + t]);
  }
}

__global__ void k_zsplit(const float* __restrict__ z,
                         u16* __restrict__ zh, u16* __restrict__ zl)
{
  const int i4 = blockIdx.x*256 + threadIdx.x;
  const float4 v = *(const float4*)(z + (size_t)i4*4);
  short4v h, lo;
  {
    const u16 h0 = f2bf(v.x); h[0] = (short)h0; lo[0] = (short)f2bf(v.x - bf2f(h0));
    const u16 h1 = f2bf(v.y); h[1] = (short)h1; lo[1] = (short)f2bf(v.y - bf2f(h1));
    const u16 h2 = f2bf(v.z); h[2] = (short)h2; lo[2] = (short)f2bf(v.z - bf2f(h2));
    const u16 h3 = f2bf(v.w); h[3] = (short)h3; lo[3] = (short)f2bf(v.w - bf2f(h3));
  }
  *(short4v*)(zh + (size_t)i4*4) = h;
  *(short4v*)(zl + (size_t)i4*4) = lo;
}

__global__ __launch_bounds__(256) void k_xy_mfma(const u16* __restrict__ zh,
    const u16* __restrict__ zl, const u16* __restrict__ WlT,
    const float* __restrict__ bl1, const float* __restrict__ bl2,
    float* __restrict__ X, float* __restrict__ Y)
{
  const int t = threadIdx.x;
  const int l = t & 63, w = t >> 6;
  const int r0 = blockIdx.x * 16;
  const int l15 = l & 15, kb = l >> 4;
  const int c0 = w * 128;
  f32x4 acc[8];
#pragma unroll
  for (int fi = 0; fi < 8; ++fi) { acc[fi][0]=0.f; acc[fi][1]=0.f; acc[fi][2]=0.f; acc[fi][3]=0.f; }
  const u16* ah = zh + (size_t)(r0 + l15)*DD + kb*8;
  const u16* al = zl + (size_t)(r0 + l15)*DD + kb*8;
#pragma unroll 1
  for (int kk = 0; kk < DD; kk += 32) {
    const short8v a0 = *(const short8v*)(ah + kk);
    const short8v a1 = *(const short8v*)(al + kk);
#pragma unroll
    for (int fi = 0; fi < 8; ++fi) {
      const short8v b = *(const short8v*)(WlT + (size_t)(c0 + fi*16 + l15)*DD + kk + kb*8);
      acc[fi] = __builtin_amdgcn_mfma_f32_16x16x32_bf16(a0, b, acc[fi], 0, 0, 0);
      acc[fi] = __builtin_amdgcn_mfma_f32_16x16x32_bf16(a1, b, acc[fi], 0, 0, 0);
    }
  }
#pragma unroll
  for (int fi = 0; fi < 8; ++fi) {
    const int cg = c0 + fi*16 + l15;
    float* dst = (cg < 256) ? X : Y;
    const float bias = (cg < 256) ? bl1[cg] : bl2[cg - 256];
    const int c = cg & 255;
#pragma unroll
    for (int j = 0; j < 4; ++j) {
      const int gr = r0 + kb*4 + j;
      dst[(size_t)gr*DD + c] = 1.f / (1.f + expf(-(acc[fi][j] + bias)));
    }
  }
}

__global__ __launch_bounds__(256) void k_edge(const float* __restrict__ X,
    const float* __restrict__ Y, const int* __restrict__ ddi,
    const float* __restrict__ attr,
    const float* __restrict__ Wl3, const float* __restrict__ bl3,
    float* __restrict__ out)
{
  __shared__ __align__(16) float s_a[8*68];
  __shared__ __align__(16) float s_r[8*257];
  const int t = threadIdx.x;
  const int e0 = blockIdx.x * 8;
  for (int idx = t; idx < 8*64; idx += 256) {
    const int r = idx >> 6, k = idx & 63;
    s_a[r*68 + k] = attr[(size_t)(e0 + r)*NFF + k];
  }
  __syncthreads();
  float acc[8];
#pragma unroll
  for (int r = 0; r < 8; ++r) acc[r] = bl3[t];
#pragma unroll 4
  for (int k = 0; k < 64; ++k) {
    const float w = Wl3[(size_t)k*DD + t];
#pragma unroll
    for (int r = 0; r < 8; ++r) acc[r] = fmaf(s_a[r*68 + k], w, acc[r]);
  }
#pragma unroll
  for (int r = 0; r < 8; ++r) {
    const int e = e0 + r;
    const int s = ddi[e], d = ddi[E2B + e];
    const float xv = X[(size_t)s*DD + t];
    const float yv = Y[(size_t)d*DD + t];
    const float av = 1.f / (1.f + expf(-acc[r]));
    const float lp = xv + av - yv;
    s_r[r*257 + t] = lp * lp;
    if (e < BB) out[12288 + (size_t)e*DD + t] = xv;
  }
  __syncthreads();
  {
    const int row = t >> 5, l = t & 31;
    float s = 0.f;
#pragma unroll
    for (int j = 0; j < 8; ++j) s += s_r[row*257 + l + 32*j];
#pragma unroll
    for (int off = 16; off >= 1; off >>= 1) s += __shfl_xor(s, off);
    if (l == 0) {
      const float nrm = sqrtf(s);
      const int e = e0 + row;
      if (e < BB) out[4096 + e] = nrm;
      else        out[8192 + (e - BB)] = nrm;
    }
  }
}

__global__ void k_loss(float* __restrict__ out) {
  int i = blockIdx.x*256 + threadIdx.x;
  if (i < BB) out[i] = 2.f*(float)DD - out[4096 + i] + 0.5f*out[8192 + i];
}

// ============================================================

extern "C" void kernel_launch(void* const* d_in, const int* in_sizes, int n_in,
                              void* d_out, int out_size, void* d_ws, size_t ws_size,
                              hipStream_t stream)
{
  const float* x    = (const float*)d_in[0];
  const int*   esrc = (const int*)d_in[1];
  const int*   edst = (const int*)d_in[2];
  const float* ewt  = (const float*)d_in[3];
  const int*   ddi  = (const int*)d_in[4];
  const float* attr = (const float*)d_in[5];
  const float* W1   = (const float*)d_in[6];  const float* b1  = (const float*)d_in[7];
  const float* Ws1r = (const float*)d_in[8];  const float* Ws1n= (const float*)d_in[9];  const float* bs1 = (const float*)d_in[10];
  const float* W2   = (const float*)d_in[11]; const float* b2  = (const float*)d_in[12];
  const float* Ws2r = (const float*)d_in[13]; const float* Ws2n= (const float*)d_in[14]; const float* bs2 = (const float*)d_in[15];
  const float* W3   = (const float*)d_in[16]; const float* b3  = (const float*)d_in[17];
  const float* Ws3r = (const float*)d_in[18]; const float* Ws3n= (const float*)d_in[19]; const float* bs3 = (const float*)d_in[20];
  const float* Wd   = (const float*)d_in[21]; const float* bd  = (const float*)d_in[22];
  const float* Wl1  = (const float*)d_in[23]; const float* bl1 = (const float*)d_in[24];
  const float* Wl2  = (const float*)d_in[25]; const float* bl2 = (const float*)d_in[26];
  const float* Wl3  = (const float*)d_in[27]; const float* bl3 = (const float*)d_in[28];

  float* ws = (float*)d_ws;
  u16*  featB = (u16*)ws;                          // GG*768 bf16
  float* hdd  = ws + 3840000;                      // GG*256 f32
  float* zb   = hdd + (size_t)GG*DD;
  float* degf = zb  + (size_t)GG*DD;
  u16*  zh    = (u16*)(degf + GG);                 // GG*256 bf16
  u16*  zl    = zh + (size_t)GG*DD;
  u16*  WdT   = zl + (size_t)GG*DD;                // 256*768 bf16
  u16*  WlT   = WdT + 256*SIXH;                    // 512*256 bf16
  _Float16* WgT = (_Float16*)(WlT + 512*DD);       // 81920 fp16 (graph W splits)
  float* Xb   = ws;                                // overlay featB (dead after ddi gemm)
  float* Yb   = hdd;                               // overlay hdd (dead after scatter)
  float* out  = (float*)d_out;

  k_convW<<<768, 256, 0, stream>>>(Wd, Wl1, Wl2, WdT, WlT);
  k_convW123<<<128, 128, 0, stream>>>(W1, W2, W3, WgT);
  graph_kernel<<<GG, 256, 0, stream>>>(x, esrc, edst, ewt, WgT,
      b1, Ws1r, Ws1n, bs1, b2, Ws2r, Ws2n, bs2, b3, Ws3r, Ws3n, bs3, featB);
  k_deg_init<<<(GG + 255)/256, 256, 0, stream>>>(degf);
  k_deg_acc<<<(E2B + 255)/256, 256, 0, stream>>>(ddi, degf);
  k_ddi_mfma<<<GG/16, 256, 0, stream>>>(featB, WdT, degf, bd, hdd, zb);
  k_scatter<<<E2B/4, 256, 0, stream>>>(ddi, degf, hdd, zb);
  k_zsplit<<<GG*DD/4/256, 256, 0, stream>>>(zb, zh, zl);
  k_xy_mfma<<<GG/16, 256, 0, stream>>>(zh, zl, WlT, bl1, bl2, Xb, Yb);
  k_edge<<<E2B/8, 256, 0, stream>>>(Xb, Yb, ddi, attr, Wl3, bl3, out);
  k_loss<<<(BB + 255)/256, 256, 0, stream>>>(out);
}

// Round 14
// 370.151 us; speedup vs baseline: 1.0456x; 1.0456x over previous
//
#include <hip/hip_runtime.h>
#include <math.h>

#define GG   10000
#define NN0  32
#define EE0  64
#define NFF  64
#define HH   128
#define DD   256
#define BB   4096
#define E2B  8192
#define SIXH 768
#define APAD 36

typedef unsigned short u16;
typedef __attribute__((ext_vector_type(8))) short short8v;
typedef __attribute__((ext_vector_type(4))) short short4v;
typedef __attribute__((ext_vector_type(4))) float f32x4;
typedef _Float16 h8f __attribute__((ext_vector_type(8)));
typedef _Float16 h4f __attribute__((ext_vector_type(4)));

static __device__ __forceinline__ u16 f2bf(float x) {
  unsigned u = __float_as_uint(x);
  return (u16)((u + 0x7FFFu + ((u >> 16) & 1u)) >> 16);   // RTNE
}
static __device__ __forceinline__ float bf2f(u16 h) {
  return __uint_as_float(((unsigned)h) << 16);
}

// ============================================================
// Per-graph fused pipeline (round-11 structure — best measured).
// P3 (y@W) on MFMA via fp16 hi/lo split (3-product, fp32-class).
// v1/v2 via deterministic per-wave partial slots. ~32 KB LDS.
// ============================================================

template<int M, int KK, int K, int SX, bool IND, bool LAST>
__device__ __forceinline__ void stage(
    const _Float16* __restrict__ WTh, const _Float16* __restrict__ WTl,
    const float* __restrict__ bg,
    const float* __restrict__ Wr, const float* __restrict__ Wn, const float* __restrict__ bs,
    float* bufX, _Float16* ybh, _Float16* ybl, float* s_A,
    float* s_dis, float* s_cm, float* s_sc2,
    float* s_v1p, float* s_v2p, float* s_score, int* s_rank, int* s_inv,
    int& src_r, int& dst_r, float& ew_r,
    u16* __restrict__ featg, int t)
{
  constexpr int KP = K + 8;
  constexpr int RT  = (M > 16) ? 2 : 1;
  constexpr int CTW = (RT == 2) ? 4 : 2;
  constexpr int KF  = K / 32;
  constexpr int NS  = (RT == 2) ? 2 : 4;

  // P0: raw A[dst][src] += ew via LDS atomics (wave 0, one edge per lane)
  if (t < EE0)
    atomicAdd(&s_A[dst_r*APAD + src_r], ew_r);
  __syncthreads();

  // P1: deg = 1 + row-sum(A) -> dis; cm = dis*g; sc2 = dis^2*g
  if (t < M) {
    float deg = 1.f;
#pragma unroll
    for (int m0 = 0; m0 < M; m0 += 4) {
      const float4 a4 = *(const float4*)(s_A + t*APAD + m0);
      deg += a4.x + a4.y + a4.z + a4.w;
    }
    const float dis = rsqrtf(deg);
    const float gg = IND ? s_score[s_inv[t]] : 1.f;
    s_dis[t] = dis; s_cm[t] = dis*gg; s_sc2[t] = dis*dis*gg;
  }
  __syncthreads();

  // P2: y[r] = dis_r * sum_m A[r,m]*cm[m]*x[ind(m)] + sc2[r]*x[ind(r)]
  //     written as fp16 hi + (residual*2048) lo
  {
    constexpr int CGB = K/4, RGB = 256/CGB, R = M/RGB;
    const int cg = t % CGB, rg = t / CGB;
    const int c0 = cg * 4;
    float acc[R][4];
#pragma unroll
    for (int i = 0; i < R; ++i) { acc[i][0]=0.f; acc[i][1]=0.f; acc[i][2]=0.f; acc[i][3]=0.f; }
#pragma unroll 2
    for (int m0 = 0; m0 < M; m0 += 4) {
      float4 a[R];
#pragma unroll
      for (int i = 0; i < R; ++i)
        a[i] = *(const float4*)(s_A + (rg*R + i)*APAD + m0);
#pragma unroll
      for (int j = 0; j < 4; ++j) {
        const int m = m0 + j;
        const int row = IND ? s_inv[m] : m;
        const float4 xv = *(const float4*)(bufX + row*SX + c0);
        const float cmm = s_cm[m];
#pragma unroll
        for (int i = 0; i < R; ++i) {
          const float aj = (j==0) ? a[i].x : (j==1) ? a[i].y : (j==2) ? a[i].z : a[i].w;
          const float cf = aj * cmm;
          acc[i][0] = fmaf(cf, xv.x, acc[i][0]);
          acc[i][1] = fmaf(cf, xv.y, acc[i][1]);
          acc[i][2] = fmaf(cf, xv.z, acc[i][2]);
          acc[i][3] = fmaf(cf, xv.w, acc[i][3]);
        }
      }
    }
#pragma unroll
    for (int i = 0; i < R; ++i) {
      const int r = rg*R + i;
      const int rr = IND ? s_inv[r] : r;
      const float4 xv = *(const float4*)(bufX + rr*SX + c0);
      const float dr = s_dis[r], sc = s_sc2[r];
      float4 v;
      v.x = fmaf(sc, xv.x, acc[i][0]*dr);
      v.y = fmaf(sc, xv.y, acc[i][1]*dr);
      v.z = fmaf(sc, xv.z, acc[i][2]*dr);
      v.w = fmaf(sc, xv.w, acc[i][3]*dr);
      h4f vh, vl;
      _Float16 h;
      h = (_Float16)v.x; vh[0] = h; vl[0] = (_Float16)((v.x - (float)h) * 2048.f);
      h = (_Float16)v.y; vh[1] = h; vl[1] = (_Float16)((v.y - (float)h) * 2048.f);
      h = (_Float16)v.z; vh[2] = h; vl[2] = (_Float16)((v.z - (float)h) * 2048.f);
      h = (_Float16)v.w; vh[3] = h; vl[3] = (_Float16)((v.w - (float)h) * 2048.f);
      *(h4f*)(ybh + r*KP + c0) = vh;
      *(h4f*)(ybl + r*KP + c0) = vl;
    }
  }
  __syncthreads();

  // P3 (MFMA): out = relu(y @ W + b) -> bufX; v1/v2 partials -> slots
  {
    const int l = t & 63, w = t >> 6;
    const int l15 = l & 15, kb = l >> 4;
    const int rt   = (RT == 2) ? (w >> 1) : 0;
    const int ct0  = (RT == 2) ? ((w & 1) * CTW) : (w * CTW);
    const int slot = (RT == 2) ? (w & 1) : w;

    h8f ah[KF], al[KF];
#pragma unroll
    for (int kf = 0; kf < KF; ++kf) {
      ah[kf] = *(const h8f*)(ybh + (rt*16 + l15)*KP + kf*32 + kb*8);
      al[kf] = *(const h8f*)(ybl + (rt*16 + l15)*KP + kf*32 + kb*8);
    }
    float p1[4] = {0.f,0.f,0.f,0.f}, p2[4] = {0.f,0.f,0.f,0.f};
#pragma unroll
    for (int ci = 0; ci < CTW; ++ci) {
      const int ct = ct0 + ci;
      const int col = ct*16 + l15;
      f32x4 a0 = {0.f,0.f,0.f,0.f}, a1 = {0.f,0.f,0.f,0.f};
#pragma unroll
      for (int kf = 0; kf < KF; ++kf) {
        const h8f bh = *(const h8f*)(WTh + (size_t)col*K + kf*32 + kb*8);
        const h8f bl = *(const h8f*)(WTl + (size_t)col*K + kf*32 + kb*8);
        a0 = __builtin_amdgcn_mfma_f32_16x16x32_f16(ah[kf], bh, a0, 0, 0, 0);
        a1 = __builtin_amdgcn_mfma_f32_16x16x32_f16(ah[kf], bl, a1, 0, 0, 0);
        a1 = __builtin_amdgcn_mfma_f32_16x16x32_f16(al[kf], bh, a1, 0, 0, 0);
      }
      const float bb = bg[col], wnc = Wn[col], wrc = Wr[col];
#pragma unroll
      for (int j = 0; j < 4; ++j) {
        const int row = rt*16 + kb*4 + j;
        const float o = fmaxf(fmaf(a1[j], (1.f/2048.f), a0[j]) + bb, 0.f);
        bufX[row*HH + col] = o;
        p1[j] = fmaf(o, wnc, p1[j]);
        p2[j] = fmaf(o, wrc, p2[j]);
      }
    }
#pragma unroll
    for (int j = 0; j < 4; ++j) {
#pragma unroll
      for (int off = 8; off >= 1; off >>= 1) {
        p1[j] += __shfl_xor(p1[j], off);
        p2[j] += __shfl_xor(p2[j], off);
      }
    }
    if (l15 == 0) {
#pragma unroll
      for (int j = 0; j < 4; ++j) {
        const int row = rt*16 + kb*4 + j;
        s_v1p[slot*32 + row] = p1[j];
        s_v2p[slot*32 + row] = p2[j];
      }
    }
  }
  __syncthreads();

  // P45 (wave 0): score -> rank -> inv -> edge remap (slot-sum, deterministic)
  if (t < 64) {
    float v1t = 0.f, v2t = 0.f;
    if (t < M) {
      v2t = s_v2p[t] + s_v2p[32 + t];
      if (NS == 4) v2t += s_v2p[64 + t] + s_v2p[96 + t];
      float sc = bs[0] + v2t;
#pragma unroll
      for (int m0 = 0; m0 < M; m0 += 4) {
        const float4 a4 = *(const float4*)(s_A + t*APAD + m0);
        float4 v4 = *(const float4*)(s_v1p + m0);
        const float4 vb = *(const float4*)(s_v1p + 32 + m0);
        v4.x += vb.x; v4.y += vb.y; v4.z += vb.z; v4.w += vb.w;
        if (NS == 4) {
          const float4 vc = *(const float4*)(s_v1p + 64 + m0);
          const float4 vd = *(const float4*)(s_v1p + 96 + m0);
          v4.x += vc.x + vd.x; v4.y += vc.y + vd.y;
          v4.z += vc.z + vd.z; v4.w += vc.w + vd.w;
        }
        sc += a4.x*v4.x + a4.y*v4.y + a4.z*v4.z + a4.w*v4.w;
      }
      s_score[t] = tanhf(sc);
    }
    if (t < M) {
      const float st = s_score[t];
      int r = 0;
      for (int m = 0; m < M; ++m) {
        const float sm = s_score[m];
        r += (sm > st) || (sm == st && m < t);
      }
      s_rank[t] = r;
      if (r < KK) s_inv[r] = t;
    }
    if (!LAST) {
      const int a = s_rank[src_r];
      const int b = s_rank[dst_r];
      const bool val = (a < KK) && (b < KK);
      ew_r  = val ? ew_r : 0.f;
      src_r = val ? a : 0;
      dst_r = val ? b : 0;
    }
  }
  __syncthreads();

  // P6: readout (gmp || gap) -> bf16 feat; zero A for next stage
  {
    const int f = t & 127, which = t >> 7;
    float r_acc = which ? 0.f : -INFINITY;
#pragma unroll
    for (int r = 0; r < KK; ++r) {
      const int n = s_inv[r];
      const float v = bufX[n*HH + f] * s_score[n];
      r_acc = which ? (r_acc + v) : fmaxf(r_acc, v);
    }
    featg[which*HH + f] = f2bf(which ? r_acc * (1.f/KK) : r_acc);
  }
  if (!LAST) {
    for (int idx = t; idx < NN0*APAD/4; idx += 256) {
      float4 z4; z4.x = 0.f; z4.y = 0.f; z4.z = 0.f; z4.w = 0.f;
      *(float4*)(s_A + idx*4) = z4;
    }
  }
  __syncthreads();
}

__global__ __launch_bounds__(256, 5) void graph_kernel(
    const float* __restrict__ x,
    const int* __restrict__ esrc, const int* __restrict__ edst, const float* __restrict__ ewg,
    const _Float16* __restrict__ WT,
    const float* __restrict__ b1,
    const float* __restrict__ Ws1r, const float* __restrict__ Ws1n, const float* __restrict__ bs1,
    const float* __restrict__ b2,
    const float* __restrict__ Ws2r, const float* __restrict__ Ws2n, const float* __restrict__ bs2,
    const float* __restrict__ b3,
    const float* __restrict__ Ws3r, const float* __restrict__ Ws3n, const float* __restrict__ bs3,
    u16* __restrict__ featB)
{
  __shared__ __align__(16) float bufX[NN0*HH];            // 16 KB
  __shared__ __align__(16) _Float16 ybh[2304], ybl[2304]; // 9 KB
  __shared__ __align__(16) float s_A[NN0*APAD];           // 4.5 KB
  __shared__ __align__(16) float s_dis[NN0], s_cm[NN0], s_sc2[NN0], s_score[NN0];
  __shared__ __align__(16) float s_v1p[128], s_v2p[128];
  __shared__ __align__(16) int   s_rank[NN0], s_inv[NN0];

  const int t = threadIdx.x;
  const int g = blockIdx.x;

  for (int idx = t; idx < NN0*NFF/4; idx += 256)
    *(float4*)(bufX + idx*4) = *(const float4*)(x + (size_t)g*NN0*NFF + idx*4);
  int src_r, dst_r; float ew_r;
  {
    const int e = g*EE0 + (t & 63);
    src_r = esrc[e] - g*NN0;
    dst_r = edst[e] - g*NN0;
    ew_r  = ewg[e];
  }
  for (int idx = t; idx < NN0*APAD/4; idx += 256) {
    float4 z4; z4.x = 0.f; z4.y = 0.f; z4.z = 0.f; z4.w = 0.f;
    *(float4*)(s_A + idx*4) = z4;
  }
  __syncthreads();

  u16* featg = featB + (size_t)g * SIXH;
  const _Float16* W1h = WT;
  const _Float16* W1l = W1h + 128*64;
  const _Float16* W2h = W1l + 128*64;
  const _Float16* W2l = W2h + 128*128;
  const _Float16* W3h = W2l + 128*128;
  const _Float16* W3l = W3h + 128*128;

  stage<NN0, 16, NFF, NFF, false, false>(W1h, W1l, b1, Ws1r, Ws1n, bs1,
      bufX, ybh, ybl, s_A, s_dis, s_cm, s_sc2, s_v1p, s_v2p, s_score, s_rank, s_inv,
      src_r, dst_r, ew_r, featg, t);
  stage<16, 8, HH, HH, true, false>(W2h, W2l, b2, Ws2r, Ws2n, bs2,
      bufX, ybh, ybl, s_A, s_dis, s_cm, s_sc2, s_v1p, s_v2p, s_score, s_rank, s_inv,
      src_r, dst_r, ew_r, featg + 256, t);
  stage<8, 4, HH, HH, true, true>(W3h, W3l, b3, Ws3r, Ws3n, bs3,
      bufX, ybh, ybl, s_A, s_dis, s_cm, s_sc2, s_v1p, s_v2p, s_score, s_rank, s_inv,
      src_r, dst_r, ew_r, featg + 512, t);
}

// convert graph-stage weights into fp16 hi/lo, fragment-transposed [col][k]
__global__ void k_convW123(const float* __restrict__ W1, const float* __restrict__ W2,
                           const float* __restrict__ W3, _Float16* __restrict__ T)
{
  const int c = blockIdx.x;
  const int k = threadIdx.x;
  _Float16* W1h = T;
  _Float16* W1l = W1h + 128*64;
  _Float16* W2h = W1l + 128*64;
  _Float16* W2l = W2h + 128*128;
  _Float16* W3h = W2l + 128*128;
  _Float16* W3l = W3h + 128*128;
  if (k < 64) {
    const float v = W1[(size_t)k*HH + c];
    const _Float16 h = (_Float16)v;
    W1h[c*64 + k] = h;
    W1l[c*64 + k] = (_Float16)((v - (float)h) * 2048.f);
  }
  {
    const float v = W2[(size_t)k*HH + c];
    const _Float16 h = (_Float16)v;
    W2h[c*HH + k] = h;
    W2l[c*HH + k] = (_Float16)((v - (float)h) * 2048.f);
  }
  {
    const float v = W3[(size_t)k*HH + c];
    const _Float16 h = (_Float16)v;
    W3h[c*HH + k] = h;
    W3l[c*HH + k] = (_Float16)((v - (float)h) * 2048.f);
  }
}

// ============================================================
// DDI stage — bf16 MFMA GEMMs
// ============================================================

__global__ void k_convW(const float* __restrict__ Wd,
                        const float* __restrict__ Wl1, const float* __restrict__ Wl2,
                        u16* __restrict__ WdT, u16* __restrict__ WlT)
{
  const int b = blockIdx.x, t = threadIdx.x;
  if (b < 256) {
#pragma unroll
    for (int i = 0; i < 3; ++i) {
      const int k = i*256 + t;
      WdT[(size_t)b*SIXH + k] = f2bf(Wd[(size_t)k*DD + b]);
    }
  } else {
    const int c = b - 256;
    const float* src = (c < 256) ? Wl1 : Wl2;
    WlT[(size_t)c*DD + t] = f2bf(src[(size_t)t*DD + (c & 255)]);
  }
}

__global__ void k_deg_init(float* __restrict__ degf) {
  int i = blockIdx.x*256 + threadIdx.x;
  if (i < GG) degf[i] = 1.f;
}

__global__ void k_deg_acc(const int* __restrict__ ddi, float* __restrict__ degf) {
  int e = blockIdx.x*256 + threadIdx.x;
  if (e < E2B) atomicAdd(&degf[ddi[E2B + e]], 1.f);
}

__global__ __launch_bounds__(256) void k_ddi_mfma(const u16* __restrict__ featB,
    const u16* __restrict__ WdT, const float* __restrict__ degf,
    const float* __restrict__ bd, float* __restrict__ hdd, float* __restrict__ z)
{
  const int t = threadIdx.x;
  const int l = t & 63, w = t >> 6;
  const int r0 = blockIdx.x * 16;
  const int l15 = l & 15, kb = l >> 4;
  const int c0 = w * 64;
  f32x4 acc[4];
#pragma unroll
  for (int fi = 0; fi < 4; ++fi) { acc[fi][0]=0.f; acc[fi][1]=0.f; acc[fi][2]=0.f; acc[fi][3]=0.f; }
  const u16* aptr = featB + (size_t)(r0 + l15)*SIXH + kb*8;
#pragma unroll 2
  for (int kk = 0; kk < SIXH; kk += 32) {
    const short8v a = *(const short8v*)(aptr + kk);
#pragma unroll
    for (int fi = 0; fi < 4; ++fi) {
      const short8v b = *(const short8v*)(WdT + (size_t)(c0 + fi*16 + l15)*SIXH + kk + kb*8);
      acc[fi] = __builtin_amdgcn_mfma_f32_16x16x32_bf16(a, b, acc[fi], 0, 0, 0);
    }
  }
#pragma unroll
  for (int j = 0; j < 4; ++j) {
    const int gr = r0 + kb*4 + j;
    const float rd = 1.f / degf[gr];
#pragma unroll
    for (int fi = 0; fi < 4; ++fi) {
      const int c = c0 + fi*16 + l15;
      const float v = acc[fi][j];
      hdd[(size_t)gr*DD + c] = v;
      z[(size_t)gr*DD + c] = fmaf(v, rd, bd[c]);
    }
  }
}

__global__ void k_scatter(const int* __restrict__ ddi, const float* __restrict__ degf,
                          const float* __restrict__ hdd, float* __restrict__ z)
{
  const int t = threadIdx.x;
#pragma unroll
  for (int j = 0; j < 4; ++j) {
    const int e = blockIdx.x*4 + j;
    const int s = ddi[e], d = ddi[E2B + e];
    const float nrm = rsqrtf(degf[s]) * rsqrtf(degf[d]);
    atomicAdd(&z[(size_t)d*DD + t], nrm * hdd[(size_t)s*DD + t]);
  }
}

// [X|Y] = sigmoid((zh+zl) @ [Wl1|Wl2] + b); z split to bf16 h/l IN-REGISTER
__global__ __launch_bounds__(256) void k_xy_mfma(const float* __restrict__ z,
    const u16* __restrict__ WlT,
    const float* __restrict__ bl1, const float* __restrict__ bl2,
    float* __restrict__ X, float* __restrict__ Y)
{
  const int t = threadIdx.x;
  const int l = t & 63, w = t >> 6;
  const int r0 = blockIdx.x * 16;
  const int l15 = l & 15, kb = l >> 4;
  const int c0 = w * 128;
  f32x4 acc[8];
#pragma unroll
  for (int fi = 0; fi < 8; ++fi) { acc[fi][0]=0.f; acc[fi][1]=0.f; acc[fi][2]=0.f; acc[fi][3]=0.f; }
  const float* ap = z + (size_t)(r0 + l15)*DD + kb*8;
#pragma unroll 1
  for (int kk = 0; kk < DD; kk += 32) {
    short8v a0, a1;
    {
      const float4 v0 = *(const float4*)(ap + kk);
      const float4 v1 = *(const float4*)(ap + kk + 4);
#pragma unroll
      for (int u = 0; u < 8; ++u) {
        const float v = (u==0)?v0.x:(u==1)?v0.y:(u==2)?v0.z:(u==3)?v0.w
                       :(u==4)?v1.x:(u==5)?v1.y:(u==6)?v1.z:v1.w;
        const u16 h = f2bf(v);
        a0[u] = (short)h;
        a1[u] = (short)f2bf(v - bf2f(h));
      }
    }
#pragma unroll
    for (int fi = 0; fi < 8; ++fi) {
      const short8v b = *(const short8v*)(WlT + (size_t)(c0 + fi*16 + l15)*DD + kk + kb*8);
      acc[fi] = __builtin_amdgcn_mfma_f32_16x16x32_bf16(a0, b, acc[fi], 0, 0, 0);
      acc[fi] = __builtin_amdgcn_mfma_f32_16x16x32_bf16(a1, b, acc[fi], 0, 0, 0);
    }
  }
#pragma unroll
  for (int fi = 0; fi < 8; ++fi) {
    const int cg = c0 + fi*16 + l15;
    float* dst = (cg < 256) ? X : Y;
    const float bias = (cg < 256) ? bl1[cg] : bl2[cg - 256];
    const int c = cg & 255;
#pragma unroll
    for (int j = 0; j < 4; ++j) {
      const int gr = r0 + kb*4 + j;
      dst[(size_t)gr*DD + c] = 1.f / (1.f + expf(-(acc[fi][j] + bias)));
    }
  }
}

__global__ __launch_bounds__(256) void k_edge(const float* __restrict__ X,
    const float* __restrict__ Y, const int* __restrict__ ddi,
    const float* __restrict__ attr,
    const float* __restrict__ Wl3, const float* __restrict__ bl3,
    float* __restrict__ out)
{
  __shared__ __align__(16) float s_a[8*68];
  __shared__ __align__(16) float s_r[8*257];
  const int t = threadIdx.x;
  const int e0 = blockIdx.x * 8;
  for (int idx = t; idx < 8*64; idx += 256) {
    const int r = idx >> 6, k = idx & 63;
    s_a[r*68 + k] = attr[(size_t)(e0 + r)*NFF + k];
  }
  __syncthreads();
  float acc[8];
#pragma unroll
  for (int r = 0; r < 8; ++r) acc[r] = bl3[t];
#pragma unroll 4
  for (int k = 0; k < 64; ++k) {
    const float w = Wl3[(size_t)k*DD + t];
#pragma unroll
    for (int r = 0; r < 8; ++r) acc[r] = fmaf(s_a[r*68 + k], w, acc[r]);
  }
#pragma unroll
  for (int r = 0; r < 8; ++r) {
    const int e = e0 + r;
    const int s = ddi[e], d = ddi[E2B + e];
    const float xv = X[(size_t)s*DD + t];
    const float yv = Y[(size_t)d*DD + t];
    const float av = 1.f / (1.f + expf(-acc[r]));
    const float lp = xv + av - yv;
    s_r[r*257 + t] = lp * lp;
    if (e < BB) out[12288 + (size_t)e*DD + t] = xv;
  }
  __syncthreads();
  {
    const int row = t >> 5, l = t & 31;
    float s = 0.f;
#pragma unroll
    for (int j = 0; j < 8; ++j) s += s_r[row*257 + l + 32*j];
#pragma unroll
    for (int off = 16; off >= 1; off >>= 1) s += __shfl_xor(s, off);
    if (l == 0) {
      const float nrm = sqrtf(s);
      const int e = e0 + row;
      if (e < BB) out[4096 + e] = nrm;
      else        out[8192 + (e - BB)] = nrm;
    }
  }
}

__global__ void k_loss(float* __restrict__ out) {
  int i = blockIdx.x*256 + threadIdx.x;
  if (i < BB) out[i] = 2.f*(float)DD - out[4096 + i] + 0.5f*out[8192 + i];
}

// ============================================================

extern "C" void kernel_launch(void* const* d_in, const int* in_sizes, int n_in,
                              void* d_out, int out_size, void* d_ws, size_t ws_size,
                              hipStream_t stream)
{
  const float* x    = (const float*)d_in[0];
  const int*   esrc = (const int*)d_in[1];
  const int*   edst = (const int*)d_in[2];
  const float* ewt  = (const float*)d_in[3];
  const int*   ddi  = (const int*)d_in[4];
  const float* attr = (const float*)d_in[5];
  const float* W1   = (const float*)d_in[6];  const float* b1  = (const float*)d_in[7];
  const float* Ws1r = (const float*)d_in[8];  const float* Ws1n= (const float*)d_in[9];  const float* bs1 = (const float*)d_in[10];
  const float* W2   = (const float*)d_in[11]; const float* b2  = (const float*)d_in[12];
  const float* Ws2r = (const float*)d_in[13]; const float* Ws2n= (const float*)d_in[14]; const float* bs2 = (const float*)d_in[15];
  const float* W3   = (const float*)d_in[16]; const float* b3  = (const float*)d_in[17];
  const float* Ws3r = (const float*)d_in[18]; const float* Ws3n= (const float*)d_in[19]; const float* bs3 = (const float*)d_in[20];
  const float* Wd   = (const float*)d_in[21]; const float* bd  = (const float*)d_in[22];
  const float* Wl1  = (const float*)d_in[23]; const float* bl1 = (const float*)d_in[24];
  const float* Wl2  = (const float*)d_in[25]; const float* bl2 = (const float*)d_in[26];
  const float* Wl3  = (const float*)d_in[27]; const float* bl3 = (const float*)d_in[28];

  float* ws = (float*)d_ws;
  u16*  featB = (u16*)ws;                          // GG*768 bf16
  float* hdd  = ws + 3840000;                      // GG*256 f32
  float* zb   = hdd + (size_t)GG*DD;
  float* degf = zb  + (size_t)GG*DD;
  u16*  WdT   = (u16*)(degf + GG);                 // 256*768 bf16
  u16*  WlT   = WdT + 256*SIXH;                    // 512*256 bf16
  _Float16* WgT = (_Float16*)(WlT + 512*DD);       // 81920 fp16 (graph W splits)
  float* Xb   = ws;                                // overlay featB (dead after ddi gemm)
  float* Yb   = hdd;                               // overlay hdd (dead after scatter)
  float* out  = (float*)d_out;

  k_convW<<<768, 256, 0, stream>>>(Wd, Wl1, Wl2, WdT, WlT);
  k_convW123<<<128, 128, 0, stream>>>(W1, W2, W3, WgT);
  graph_kernel<<<GG, 256, 0, stream>>>(x, esrc, edst, ewt, WgT,
      b1, Ws1r, Ws1n, bs1, b2, Ws2r, Ws2n, bs2, b3, Ws3r, Ws3n, bs3, featB);
  k_deg_init<<<(GG + 255)/256, 256, 0, stream>>>(degf);
  k_deg_acc<<<(E2B + 255)/256, 256, 0, stream>>>(ddi, degf);
  k_ddi_mfma<<<GG/16, 256, 0, stream>>>(featB, WdT, degf, bd, hdd, zb);
  k_scatter<<<E2B/4, 256, 0, stream>>>(ddi, degf, hdd, zb);
  k_xy_mfma<<<GG/16, 256, 0, stream>>>(zb, WlT, bl1, bl2, Xb, Yb);
  k_edge<<<E2B/8, 256, 0, stream>>>(Xb, Yb, ddi, attr, Wl3, bl3, out);
  k_loss<<<(BB + 255)/256, 256, 0, stream>>>(out);
}